// Round 3
// baseline (492.258 us; speedup 1.0000x reference)
//
#include <hip/hip_runtime.h>
#include <hip/hip_fp16.h>

// LinearAttention (phi = elu+1). B=8 S=4096 D=512 H=8 DH=64.
// Round 7: prefetch-depth fix on the round-6 8-phase structure.
// Round-6 diagnosis: staging spread across phases left the phase-3 chunk
// only ~1 phase of latency cover before its phase-0 consumption -> per-tile
// vmcnt stall (MfmaUtil 30%). Fix (T4 proper): at phase 0 of tile t, buf^1
// is fully free, so stage ALL 4 chunks of tile t+1 there and wait vmcnt(8):
// tile t's 8 loads then have a full tile (~4 phases) of cover. Phases 1-3
// carry no staging. Second delta: k-major tile order (per k-chunk:
// (Ah,Bh),(Ah,Bl),(Al,Bh)) so Ah re-reads are L2-hot (FETCH 158->~120 MB).
// Everything else verbatim from verified round 6.
// ws: [x_hi 32|x_lo 32|Wt_hi 2|Wt_lo 2|Qf 32|Kf 32|V 32|KVp 17|Ksp|KV|Ksum]

constexpr int Ss = 4096;
constexpr int Dd = 512;
constexpr int Hh = 8;
constexpr int Mtot = 8 * 4096;  // 32768
constexpr float EPSF = 1e-6f;

typedef short v8s __attribute__((ext_vector_type(8)));
typedef float v4f __attribute__((ext_vector_type(4)));

__device__ __forceinline__ short f2bf(float f) {  // RNE fp32 -> bf16
  unsigned u = __float_as_uint(f);
  u += 0x7fff + ((u >> 16) & 1);
  return (short)(u >> 16);
}
__device__ __forceinline__ float bf2f(short s) {
  return __uint_as_float(((unsigned)(unsigned short)s) << 16);
}
__device__ __forceinline__ void async_cp16(const void* g, void* l) {
  __builtin_amdgcn_global_load_lds((__attribute__((address_space(1))) void*)g,
                                   (__attribute__((address_space(3))) void*)l, 16, 0, 0);
}

// ---------- weight prep: W[512][512] -> Wt[n][k] bf16 hi/lo (4 matrices) ----------
__global__ __launch_bounds__(256) void prep_w(
    const float* __restrict__ W0, const float* __restrict__ W1,
    const float* __restrict__ W2, const float* __restrict__ W3,
    short* __restrict__ Th, short* __restrict__ Tl)
{
  const float* W = (blockIdx.z == 0) ? W0 : (blockIdx.z == 1) ? W1
                  : (blockIdx.z == 2) ? W2 : W3;
  short* th = Th + (size_t)blockIdx.z * 512 * 512;
  short* tl = Tl + (size_t)blockIdx.z * 512 * 512;
  __shared__ float tile[32][33];
  const int t = threadIdx.x;
  const int tx = t & 31, ty = t >> 5;  // 32 x 8
  const int k0 = blockIdx.x * 32, n0 = blockIdx.y * 32;
#pragma unroll
  for (int r = 0; r < 32; r += 8)
    tile[ty + r][tx] = W[(size_t)(k0 + ty + r) * 512 + n0 + tx];
  __syncthreads();
#pragma unroll
  for (int r = 0; r < 32; r += 8) {
    const float v = tile[tx][ty + r];  // = W[k0+tx][n0+ty+r]
    const short h = f2bf(v);
    const short l = f2bf(v - bf2f(h));
    th[(size_t)(n0 + ty + r) * 512 + k0 + tx] = h;
    tl[(size_t)(n0 + ty + r) * 512 + k0 + tx] = l;
  }
}

// ---------- x split: fp32 -> bf16 hi/lo ----------
__global__ __launch_bounds__(256) void split_x(
    const float* __restrict__ X, short* __restrict__ H, short* __restrict__ L, int n4)
{
  const int i = blockIdx.x * 256 + threadIdx.x;
  if (i >= n4) return;
  const float4 x = reinterpret_cast<const float4*>(X)[i];
  short4 h, l;
  h.x = f2bf(x.x); l.x = f2bf(x.x - bf2f(h.x));
  h.y = f2bf(x.y); l.y = f2bf(x.y - bf2f(h.y));
  h.z = f2bf(x.z); l.z = f2bf(x.z - bf2f(h.z));
  h.w = f2bf(x.w); l.w = f2bf(x.w - bf2f(h.w));
  reinterpret_cast<short4*>(H)[i] = h;
  reinterpret_cast<short4*>(L)[i] = l;
}

// ---------- staging chunk: 512 threads write 8 KB of A + 8 KB of B ----------
// Chunk = (sub s, row-half rh): rows rh*128..+127 of one BK=32 sub-tile.
// LDS dest per lane = base + lane*16B (global_load_lds linear requirement):
// d = rh*4096 + t*8 shorts == (row*4 + q)*8 with row = rh*128 + t>>2, q = t&3.
// k-quad swizzle (q ^ (row>>1)&3) applied on the GLOBAL source (verified
// 0-conflict pattern). kb = tile_k_base + s*32.
__device__ __forceinline__ void stage_chunk(
    const short* __restrict__ pA, const short* __restrict__ pB,
    short* asub, short* bsub, int kb, int rh, int t)
{
  const int row = rh * 128 + (t >> 2);
  const int q = t & 3;
  const int qs = q ^ ((row >> 1) & 3);
  const size_t g = (size_t)row * 512 + kb + qs * 8;
  const int d = rh * 4096 + t * 8;
  async_cp16(pA + g, asub + d);
  async_cp16(pB + g, bsub + d);
}

// ---------- 8-phase K-loop: 24 K-tiles (BK=64), 4 phases each ----------
// Tile order is k-major: tile i -> kc = i/3 (k base kc*64), pass = i%3 with
// pass 0:(Ah,Bh) 1:(Ah,Bl) 2:(Al,Bh)  => Ah re-reads are 1 tile apart (L2-hot).
// Per tile: phase 0 stages ALL 4 chunks of tile i+1 (8 loads) into the free
// buffer, then vmcnt(8): tile i's own 8 loads (issued one full tile earlier,
// ~4 phases of cover) are drained; tile i+1's stay in flight. Phases 1-3 are
// pure {4 ds_read | barrier | 16 MFMA | barrier}.
__device__ __forceinline__ void kloop_8ph(
    const short* __restrict__ Ahb, const short* __restrict__ Alb,
    const short* __restrict__ Bhb, const short* __restrict__ Blb,
    short* asb, short* bsb,  // LDS bases, layout [2 buf][2 sub][8192]
    int wm, int wn, int mr, int kq, int t,
    v4f (&acc)[8][4])
{
  constexpr int NT = 24;
#pragma unroll
  for (int i = 0; i < 8; ++i)
#pragma unroll
    for (int j = 0; j < 4; ++j) acc[i][j] = (v4f){0.f, 0.f, 0.f, 0.f};

  int a_off[8], b_off[4];
#pragma unroll
  for (int i = 0; i < 8; ++i) {
    const int ma = wm * 128 + i * 16 + mr;
    a_off[i] = ma * 32 + (kq ^ ((ma >> 1) & 3)) * 8;
  }
#pragma unroll
  for (int j = 0; j < 4; ++j) {
    const int nb = wn * 64 + j * 16 + mr;
    b_off[j] = nb * 32 + (kq ^ ((nb >> 1) & 3)) * 8;
  }

  // prologue: stage tile 0 fully (8 loads/thread). tile 0 = (kc 0, pass 0).
#pragma unroll
  for (int c = 0; c < 4; ++c)
    stage_chunk(Ahb, Bhb, asb + (c & 1) * 8192, bsb + (c & 1) * 8192,
                (c & 1) * 32, c >> 1, t);

  for (int kt = 0; kt < NT; ++kt) {
    const int cur = kt & 1;
    const short* as0 = asb + cur * 16384;
    const short* as1 = as0 + 8192;
    const short* bs0 = bsb + cur * 16384;
    const short* bs1 = bs0 + 8192;
    short* An = asb + (cur ^ 1) * 16384;
    short* Bn = bsb + (cur ^ 1) * 16384;

    // ---- phase 0: stage whole next tile, counted wait, first MFMA group ----
    const int nx = kt + 1;
    if (nx < NT) {
      const int pass = nx % 3;
      const int kb = (nx / 3) * 64;
      const short* pA = (pass == 2) ? Alb : Ahb;
      const short* pB = (pass == 1) ? Blb : Bhb;
#pragma unroll
      for (int c = 0; c < 4; ++c)
        stage_chunk(pA, pB, An + (c & 1) * 8192, Bn + (c & 1) * 8192,
                    kb + (c & 1) * 32, c >> 1, t);
      // tile kt's 8 loads (issued a full tile ago) drain; tile nx's 8 remain.
      asm volatile("s_waitcnt vmcnt(8)" ::: "memory");
    } else {
      asm volatile("s_waitcnt vmcnt(0)" ::: "memory");
    }
    __builtin_amdgcn_s_barrier();
    asm volatile("" ::: "memory");

    v8s fb[4][2];
#pragma unroll
    for (int j = 0; j < 4; ++j) {
      fb[j][0] = *reinterpret_cast<const v8s*>(&bs0[b_off[j]]);
      fb[j][1] = *reinterpret_cast<const v8s*>(&bs1[b_off[j]]);
    }
    {
      const v8s fa00 = *reinterpret_cast<const v8s*>(&as0[a_off[0]]);
      const v8s fa01 = *reinterpret_cast<const v8s*>(&as1[a_off[0]]);
      const v8s fa10 = *reinterpret_cast<const v8s*>(&as0[a_off[1]]);
      const v8s fa11 = *reinterpret_cast<const v8s*>(&as1[a_off[1]]);
      __builtin_amdgcn_s_setprio(1);
#pragma unroll
      for (int j = 0; j < 4; ++j) {
        acc[0][j] = __builtin_amdgcn_mfma_f32_16x16x32_bf16(fa00, fb[j][0], acc[0][j], 0, 0, 0);
        acc[0][j] = __builtin_amdgcn_mfma_f32_16x16x32_bf16(fa01, fb[j][1], acc[0][j], 0, 0, 0);
        acc[1][j] = __builtin_amdgcn_mfma_f32_16x16x32_bf16(fa10, fb[j][0], acc[1][j], 0, 0, 0);
        acc[1][j] = __builtin_amdgcn_mfma_f32_16x16x32_bf16(fa11, fb[j][1], acc[1][j], 0, 0, 0);
      }
      __builtin_amdgcn_s_setprio(0);
    }
    asm volatile("" ::: "memory");
    __builtin_amdgcn_s_barrier();

    // ---- phases 1..3: pure compute ----
#pragma unroll
    for (int p = 1; p < 4; ++p) {
      const v8s fa00 = *reinterpret_cast<const v8s*>(&as0[a_off[2 * p]]);
      const v8s fa01 = *reinterpret_cast<const v8s*>(&as1[a_off[2 * p]]);
      const v8s fa10 = *reinterpret_cast<const v8s*>(&as0[a_off[2 * p + 1]]);
      const v8s fa11 = *reinterpret_cast<const v8s*>(&as1[a_off[2 * p + 1]]);
      __builtin_amdgcn_s_barrier();
      asm volatile("" ::: "memory");
      __builtin_amdgcn_s_setprio(1);
#pragma unroll
      for (int j = 0; j < 4; ++j) {
        acc[2 * p][j] =
            __builtin_amdgcn_mfma_f32_16x16x32_bf16(fa00, fb[j][0], acc[2 * p][j], 0, 0, 0);
        acc[2 * p][j] =
            __builtin_amdgcn_mfma_f32_16x16x32_bf16(fa01, fb[j][1], acc[2 * p][j], 0, 0, 0);
        acc[2 * p + 1][j] =
            __builtin_amdgcn_mfma_f32_16x16x32_bf16(fa10, fb[j][0], acc[2 * p + 1][j], 0, 0, 0);
        acc[2 * p + 1][j] =
            __builtin_amdgcn_mfma_f32_16x16x32_bf16(fa11, fb[j][1], acc[2 * p + 1][j], 0, 0, 0);
      }
      __builtin_amdgcn_s_setprio(0);
      asm volatile("" ::: "memory");
      __builtin_amdgcn_s_barrier();
    }
  }
}

// ---------- fused QKV GEMM, 256x256 tile, 8-phase pipeline ----
// grid (Mtot/256, 6): y = mat*2 + colhalf. phi for q,k; fp16 outputs.
__global__ __launch_bounds__(512, 2) void gemm_qkv(
    const short* __restrict__ Ah, const short* __restrict__ Al,
    const short* __restrict__ Wth, const short* __restrict__ Wtl,
    const float* __restrict__ bq, const float* __restrict__ bk,
    const float* __restrict__ bv,
    __half* __restrict__ Qf, __half* __restrict__ Kf, __half* __restrict__ Vv)
{
  __shared__ __align__(16) short As[2][2][8192];  // 64 KB
  __shared__ __align__(16) short Bs[2][2][8192];  // 64 KB

  const int mat = blockIdx.y >> 1;
  const int col0 = (blockIdx.y & 1) * 256;
  const int row0 = blockIdx.x * 256;
  const float* bias = (mat == 0) ? bq : (mat == 1) ? bk : bv;
  __half* Co = (mat == 0) ? Qf : (mat == 1) ? Kf : Vv;
  const int act = (mat < 2);

  const short* Ahb = Ah + (size_t)row0 * 512;
  const short* Alb = Al + (size_t)row0 * 512;
  const short* Bhb = Wth + (size_t)mat * 512 * 512 + (size_t)col0 * 512;
  const short* Blb = Wtl + (size_t)mat * 512 * 512 + (size_t)col0 * 512;

  const int t = threadIdx.x;
  const int lane = t & 63;
  const int wv = t >> 6;                 // 8 waves
  const int wm = wv >> 2, wn = wv & 3;   // 2M x 4N -> per-wave 128x64 out
  const int mr = lane & 15, kq = lane >> 4;

  v4f acc[8][4];
  kloop_8ph(Ahb, Alb, Bhb, Blb, &As[0][0][0], &Bs[0][0][0], wm, wn, mr, kq, t, acc);

  // epilogue: C/D layout col = lane&15, row = kq*4 + r (verified math)
#pragma unroll
  for (int j = 0; j < 4; ++j) {
    const int nc = col0 + wn * 64 + j * 16 + mr;
    const float bz = bias[nc];
#pragma unroll
    for (int i = 0; i < 8; ++i) {
      const int mbase = row0 + wm * 128 + i * 16 + kq * 4;
#pragma unroll
      for (int r = 0; r < 4; ++r) {
        float v = acc[i][j][r] + bz;
        if (act) v = (v > 0.f) ? (v + 1.f) : __expf(v);
        Co[(size_t)(mbase + r) * 512 + nc] = __float2half(v);
      }
    }
  }
}

// ---------- final GEMM: out = attn @ Wo + bo, same 8-phase structure ----
__global__ __launch_bounds__(512, 2) void gemm_split(
    const short* __restrict__ Ah, const short* __restrict__ Al,
    const short* __restrict__ Bh, const short* __restrict__ Bl,
    const float* __restrict__ bias, float* __restrict__ Cf)
{
  __shared__ __align__(16) short As[2][2][8192];
  __shared__ __align__(16) short Bs[2][2][8192];

  const int col0 = blockIdx.y * 256;
  const int row0 = blockIdx.x * 256;

  const short* Ahb = Ah + (size_t)row0 * 512;
  const short* Alb = Al + (size_t)row0 * 512;
  const short* Bhb = Bh + (size_t)col0 * 512;
  const short* Blb = Bl + (size_t)col0 * 512;

  const int t = threadIdx.x;
  const int lane = t & 63;
  const int wv = t >> 6;
  const int wm = wv >> 2, wn = wv & 3;
  const int mr = lane & 15, kq = lane >> 4;

  v4f acc[8][4];
  kloop_8ph(Ahb, Alb, Bhb, Blb, &As[0][0][0], &Bs[0][0][0], wm, wn, mr, kq, t, acc);

#pragma unroll
  for (int j = 0; j < 4; ++j) {
    const int nc = col0 + wn * 64 + j * 16 + mr;
    const float bz = bias[nc];
#pragma unroll
    for (int i = 0; i < 8; ++i) {
      const int mbase = row0 + wm * 128 + i * 16 + kq * 4;
#pragma unroll
      for (int r = 0; r < 4; ++r) Cf[(size_t)(mbase + r) * 512 + nc] = acc[i][j][r] + bz;
    }
  }
}

// ---------- KV stage 1 (verbatim): partial Kf^T@V and sum Kf ----------
__global__ __launch_bounds__(256) void kv_stage1(
    const __half* __restrict__ Kf, const __half* __restrict__ V,
    float* __restrict__ KVp, float* __restrict__ Ksp)
{
  const int sc = blockIdx.x, bh = blockIdx.y;
  const int b = bh >> 3, h = bh & 7;
  __shared__ float Ks[64][68];
  __shared__ float Vs[64][68];
  const int tid = threadIdx.x;
  const int dx = (tid >> 4) * 4;
  const int mx = (tid & 15) * 4;
  float acc[4][4];
#pragma unroll
  for (int i = 0; i < 4; ++i)
#pragma unroll
    for (int j = 0; j < 4; ++j) acc[i][j] = 0.f;
  float ksum_acc = 0.f;
  const size_t base = (size_t)b * Ss * Dd + (size_t)h * 64;

  for (int s0 = sc * 256; s0 < sc * 256 + 256; s0 += 64) {
#pragma unroll
    for (int l = 0; l < 2; ++l) {
      const int idx = tid + l * 256;
      const int rr = idx >> 3, cq = idx & 7;
      const size_t g = base + (size_t)(s0 + rr) * Dd + cq * 8;
      const __half2* k2 = reinterpret_cast<const __half2*>(Kf + g);
      const __half2* v2 = reinterpret_cast<const __half2*>(V + g);
#pragma unroll
      for (int u = 0; u < 4; ++u) {
        const float2 kf = __half22float2(k2[u]);
        const float2 vf = __half22float2(v2[u]);
        Ks[rr][cq * 8 + u * 2] = kf.x; Ks[rr][cq * 8 + u * 2 + 1] = kf.y;
        Vs[rr][cq * 8 + u * 2] = vf.x; Vs[rr][cq * 8 + u * 2 + 1] = vf.y;
      }
    }
    __syncthreads();
#pragma unroll 4
    for (int s = 0; s < 64; ++s) {
      const float4 kd = *reinterpret_cast<const float4*>(&Ks[s][dx]);
      const float4 vm = *reinterpret_cast<const float4*>(&Vs[s][mx]);
      const float ka[4] = {kd.x, kd.y, kd.z, kd.w};
      const float va[4] = {vm.x, vm.y, vm.z, vm.w};
#pragma unroll
      for (int i = 0; i < 4; ++i)
#pragma unroll
        for (int j = 0; j < 4; ++j) acc[i][j] = fmaf(ka[i], va[j], acc[i][j]);
    }
    if (tid < 64) {
#pragma unroll 8
      for (int s = 0; s < 64; ++s) ksum_acc += Ks[s][tid];
    }
    __syncthreads();
  }

  const size_t pb = (size_t)(sc * 64 + bh);
#pragma unroll
  for (int i = 0; i < 4; ++i) {
    const float4 ov = {acc[i][0], acc[i][1], acc[i][2], acc[i][3]};
    *reinterpret_cast<float4*>(&KVp[(pb * 64 + dx + i) * 64 + mx]) = ov;
  }
  if (tid < 64) Ksp[pb * 64 + tid] = ksum_acc;
}

// ---------- KV stage 2 (verbatim): sum 16 partials ----------
__global__ __launch_bounds__(256) void kv_stage2(
    const float* __restrict__ KVp, const float* __restrict__ Ksp,
    float* __restrict__ KV, float* __restrict__ Ksum)
{
  const int bh = blockIdx.x, t = threadIdx.x;
  for (int e = t; e < 4096; e += 256) {
    float s = 0.f;
#pragma unroll
    for (int sc = 0; sc < 16; ++sc) s += KVp[((size_t)(sc * 64 + bh) << 12) + e];
    KV[(size_t)bh * 4096 + e] = s;
  }
  if (t < 64) {
    float s = 0.f;
#pragma unroll
    for (int sc = 0; sc < 16; ++sc) s += Ksp[(size_t)(sc * 64 + bh) * 64 + t];
    Ksum[bh * 64 + t] = s;
  }
}

// ---------- attn (verbatim): Z * (Qf @ KV), bf16 hi/lo split out -----
__global__ __launch_bounds__(256) void attn_combine(
    const __half* __restrict__ Qf, const float* __restrict__ KV,
    const float* __restrict__ Ksum, short* __restrict__ Oh, short* __restrict__ Ol)
{
  const int h = blockIdx.y;
  const int r0 = blockIdx.x * 64;
  const int b = r0 >> 12;
  const int bh = b * Hh + h;
  __shared__ float Qs[64][68];
  __shared__ float KVs[64][68];
  __shared__ float Ksums[64];
  __shared__ float Zs[64];
  const int tid = threadIdx.x;

#pragma unroll
  for (int l = 0; l < 2; ++l) {
    const int idx = tid + l * 256;
    const int rr = idx >> 3, cq = idx & 7;
    const __half2* q2 = reinterpret_cast<const __half2*>(
        Qf + (size_t)(r0 + rr) * Dd + h * 64 + cq * 8);
#pragma unroll
    for (int u = 0; u < 4; ++u) {
      const float2 qf = __half22float2(q2[u]);
      Qs[rr][cq * 8 + u * 2] = qf.x; Qs[rr][cq * 8 + u * 2 + 1] = qf.y;
    }
  }
#pragma unroll
  for (int l = 0; l < 4; ++l) {
    const int idx = tid + l * 256;
    const int rr = idx >> 4, cq = idx & 15;
    *reinterpret_cast<float4*>(&KVs[rr][cq * 4]) = *reinterpret_cast<const float4*>(
        &KV[(size_t)bh * 4096 + rr * 64 + cq * 4]);
  }
  if (tid < 64) Ksums[tid] = Ksum[bh * 64 + tid];
  __syncthreads();

  if (tid < 64) {
    float z = 0.f;
#pragma unroll 8
    for (int d = 0; d < 64; ++d) z = fmaf(Qs[tid][d], Ksums[d], z);
    Zs[tid] = 1.f / (z + EPSF);
  }
  __syncthreads();

  const int rx = (tid >> 4) * 4, mx = (tid & 15) * 4;
  float acc[4][4];
#pragma unroll
  for (int i = 0; i < 4; ++i)
#pragma unroll
    for (int j = 0; j < 4; ++j) acc[i][j] = 0.f;

#pragma unroll 4
  for (int d = 0; d < 64; ++d) {
    const float4 vm = *reinterpret_cast<const float4*>(&KVs[d][mx]);
    const float va[4] = {vm.x, vm.y, vm.z, vm.w};
#pragma unroll
    for (int i = 0; i < 4; ++i) {
      const float q = Qs[rx + i][d];
#pragma unroll
      for (int j = 0; j < 4; ++j) acc[i][j] = fmaf(q, va[j], acc[i][j]);
    }
  }

#pragma unroll
  for (int i = 0; i < 4; ++i) {
    const float z = Zs[rx + i];
    short4 hv, lv;
    float o;
    o = acc[i][0] * z; hv.x = f2bf(o); lv.x = f2bf(o - bf2f(hv.x));
    o = acc[i][1] * z; hv.y = f2bf(o); lv.y = f2bf(o - bf2f(hv.y));
    o = acc[i][2] * z; hv.z = f2bf(o); lv.z = f2bf(o - bf2f(hv.z));
    o = acc[i][3] * z; hv.w = f2bf(o); lv.w = f2bf(o - bf2f(hv.w));
    const size_t off = (size_t)(r0 + rx + i) * Dd + h * 64 + mx;
    *reinterpret_cast<short4*>(&Oh[off]) = hv;
    *reinterpret_cast<short4*>(&Ol[off]) = lv;
  }
}

extern "C" void kernel_launch(void* const* d_in, const int* in_sizes, int n_in,
                              void* d_out, int out_size, void* d_ws, size_t ws_size,
                              hipStream_t stream) {
  const float* x  = (const float*)d_in[0];
  const float* Wq = (const float*)d_in[1];
  const float* bq = (const float*)d_in[2];
  const float* Wk = (const float*)d_in[3];
  const float* bk = (const float*)d_in[4];
  const float* Wv = (const float*)d_in[5];
  const float* bv = (const float*)d_in[6];
  const float* Wo = (const float*)d_in[7];
  const float* bo = (const float*)d_in[8];
  float* out = (float*)d_out;

  char* ws = (char*)d_ws;
  const size_t MB = (size_t)1 << 20;
  short*  x_hi  = (short*)(ws);              // 32 MB (later: attn_hi)
  short*  x_lo  = (short*)(ws + 32 * MB);    // 32 MB (later: attn_lo)
  short*  Wt_hi = (short*)(ws + 64 * MB);    // 2 MB (4 x 512x512)
  short*  Wt_lo = (short*)(ws + 66 * MB);    // 2 MB
  __half* Qf    = (__half*)(ws + 68 * MB);   // 32 MB
  __half* Kf    = (__half*)(ws + 100 * MB);  // 32 MB
  __half* Vv    = (__half*)(ws + 132 * MB);  // 32 MB
  float*  KVp   = (float*)(ws + 164 * MB);   // 17 MB
  float*  Ksp   = (float*)(ws + 181 * MB);   // 256 KB
  float*  KV    = (float*)(ws + 182 * MB);   // 1 MB
  float*  Ksum  = (float*)(ws + 183 * MB);   // 16 KB
  short*  attn_hi = x_hi;
  short*  attn_lo = x_lo;
  const size_t WSTEP = (size_t)512 * 512;

  prep_w<<<dim3(16, 16, 4), 256, 0, stream>>>(Wq, Wk, Wv, Wo, Wt_hi, Wt_lo);
  split_x<<<Mtot * Dd / 4 / 256, 256, 0, stream>>>(x, x_hi, x_lo, Mtot * Dd / 4);

  gemm_qkv<<<dim3(Mtot / 256, 6), 512, 0, stream>>>(
      x_hi, x_lo, Wt_hi, Wt_lo, bq, bk, bv, Qf, Kf, Vv);

  kv_stage1<<<dim3(16, 64), 256, 0, stream>>>(Kf, Vv, KVp, Ksp);
  kv_stage2<<<64, 256, 0, stream>>>(KVp, Ksp, KV, Ksum);
  attn_combine<<<dim3(Mtot / 64, Hh), 256, 0, stream>>>(Qf, KV, Ksum, attn_hi, attn_lo);

  gemm_split<<<dim3(Mtot / 256, 2), 512, 0, stream>>>(
      attn_hi, attn_lo, Wt_hi + 3 * WSTEP, Wt_lo + 3 * WSTEP, bo, out);
}

// Round 4
// 435.431 us; speedup vs baseline: 1.1305x; 1.1305x over previous
//
#include <hip/hip_runtime.h>
#include <hip/hip_fp16.h>

// LinearAttention (phi = elu+1). B=8 S=4096 D=512 H=8 DH=64.
// Round 8: REVERT to the verified round-4 structure (128^2 tile, 4 waves,
// 2-barrier K-loop, q-XOR pre-swizzled global_load_lds staging — measured
// 864 TF / 38.7% MfmaUtil / 0 bank conflicts), plus ONE delta: MFMA shape
// 16x16x32 -> 32x32x16. Same FLOP in half the MFMA instructions at the
// better-measured rate (2382 vs 2075 TF ubench), freeing 24 issue slots
// per wave per K-step for the staging/VALU stream. Rounds 5-7 (256^2
// 2-phase/8-phase pipelines) all regressed to 27-30% MfmaUtil and are
// abandoned. LDS layout, staging, and all non-GEMM kernels are round-4
// verbatim. 32x32 layouts: A/B row=lane&31, k=8*(lane>>5)+j; C/D
// col=lane&31, row=(reg&3)+8*(reg>>2)+4*(lane>>5).
// ws: [x_hi 32|x_lo 32|Wt_hi 2|Wt_lo 2|Qf 32|Kf 32|V 32|KVp 17|Ksp|KV|Ksum]

constexpr int Ss = 4096;
constexpr int Dd = 512;
constexpr int Hh = 8;
constexpr int Mtot = 8 * 4096;  // 32768
constexpr float EPSF = 1e-6f;

typedef short v8s __attribute__((ext_vector_type(8)));
typedef float v4f __attribute__((ext_vector_type(4)));
typedef float v16f __attribute__((ext_vector_type(16)));

__device__ __forceinline__ short f2bf(float f) {  // RNE fp32 -> bf16
  unsigned u = __float_as_uint(f);
  u += 0x7fff + ((u >> 16) & 1);
  return (short)(u >> 16);
}
__device__ __forceinline__ float bf2f(short s) {
  return __uint_as_float(((unsigned)(unsigned short)s) << 16);
}
__device__ __forceinline__ void async_cp16(const void* g, void* l) {
  __builtin_amdgcn_global_load_lds((__attribute__((address_space(1))) void*)g,
                                   (__attribute__((address_space(3))) void*)l, 16, 0, 0);
}

// ---------- weight prep: W[512][512] -> Wt[n][k] bf16 hi/lo (4 matrices) ----------
__global__ __launch_bounds__(256) void prep_w(
    const float* __restrict__ W0, const float* __restrict__ W1,
    const float* __restrict__ W2, const float* __restrict__ W3,
    short* __restrict__ Th, short* __restrict__ Tl)
{
  const float* W = (blockIdx.z == 0) ? W0 : (blockIdx.z == 1) ? W1
                  : (blockIdx.z == 2) ? W2 : W3;
  short* th = Th + (size_t)blockIdx.z * 512 * 512;
  short* tl = Tl + (size_t)blockIdx.z * 512 * 512;
  __shared__ float tile[32][33];
  const int t = threadIdx.x;
  const int tx = t & 31, ty = t >> 5;  // 32 x 8
  const int k0 = blockIdx.x * 32, n0 = blockIdx.y * 32;
#pragma unroll
  for (int r = 0; r < 32; r += 8)
    tile[ty + r][tx] = W[(size_t)(k0 + ty + r) * 512 + n0 + tx];
  __syncthreads();
#pragma unroll
  for (int r = 0; r < 32; r += 8) {
    const float v = tile[tx][ty + r];  // = W[k0+tx][n0+ty+r]
    const short h = f2bf(v);
    const short l = f2bf(v - bf2f(h));
    th[(size_t)(n0 + ty + r) * 512 + k0 + tx] = h;
    tl[(size_t)(n0 + ty + r) * 512 + k0 + tx] = l;
  }
}

// ---------- x split: fp32 -> bf16 hi/lo ----------
__global__ __launch_bounds__(256) void split_x(
    const float* __restrict__ X, short* __restrict__ H, short* __restrict__ L, int n4)
{
  const int i = blockIdx.x * 256 + threadIdx.x;
  if (i >= n4) return;
  const float4 x = reinterpret_cast<const float4*>(X)[i];
  short4 h, l;
  h.x = f2bf(x.x); l.x = f2bf(x.x - bf2f(h.x));
  h.y = f2bf(x.y); l.y = f2bf(x.y - bf2f(h.y));
  h.z = f2bf(x.z); l.z = f2bf(x.z - bf2f(h.z));
  h.w = f2bf(x.w); l.w = f2bf(x.w - bf2f(h.w));
  reinterpret_cast<short4*>(H)[i] = h;
  reinterpret_cast<short4*>(L)[i] = l;
}

// ---------- fused QKV split-bf16 MFMA GEMM (round-4 staging, 32x32x16 core) ----
// grid (Mtot/128, 12): y = mat*4 + colblock. phi for q,k; fp16 outputs.
__global__ __launch_bounds__(256) void gemm_qkv(
    const short* __restrict__ Ah, const short* __restrict__ Al,
    const short* __restrict__ Wth, const short* __restrict__ Wtl,
    const float* __restrict__ bq, const float* __restrict__ bk,
    const float* __restrict__ bv,
    __half* __restrict__ Qf, __half* __restrict__ Kf, __half* __restrict__ Vv)
{
  constexpr int K = 512;
  __shared__ short As_h[128 * 32], As_l[128 * 32], Bs_h[128 * 32], Bs_l[128 * 32];

  const int mat = blockIdx.y >> 2;
  const int col0 = (blockIdx.y & 3) * 128;
  const int row0 = blockIdx.x * 128;
  const short* Bh = Wth + (size_t)mat * K * 512;
  const short* Bl = Wtl + (size_t)mat * K * 512;
  const float* bias = (mat == 0) ? bq : (mat == 1) ? bk : bv;
  __half* Co = (mat == 0) ? Qf : (mat == 1) ? Kf : Vv;
  const int act = (mat < 2);

  const int t = threadIdx.x;
  const int lane = t & 63;
  const int wv = t >> 6;
  const int wm = wv & 1, wn = wv >> 1;
  const int lr = lane & 31, lh = lane >> 5;  // 32x32 operand: row lane&31, k-half lane>>5

  v16f acc[2][2];
#pragma unroll
  for (int i = 0; i < 2; ++i)
#pragma unroll
    for (int j = 0; j < 2; ++j)
#pragma unroll
      for (int r = 0; r < 16; ++r) acc[i][j][r] = 0.f;

  const int srow = t >> 2;
  const int spq = t & 3;

  for (int k0 = 0; k0 < K; k0 += 32) {
#pragma unroll
    for (int c = 0; c < 2; ++c) {
      const int m = c * 64 + srow;
      const int q = spq ^ ((m >> 1) & 3);
      const size_t ga = (size_t)(row0 + m) * K + k0 + q * 8;
      const size_t gb = (size_t)(col0 + m) * K + k0 + q * 8;
      const int lo = c * 2048 + wv * 512;
      async_cp16(Ah + ga, As_h + lo);
      async_cp16(Al + ga, As_l + lo);
      async_cp16(Bh + gb, Bs_h + lo);
      async_cp16(Bl + gb, Bs_l + lo);
    }
    __syncthreads();

    // fragments: frag (i, ksub s): row = w*64 + i*32 + lr, k-quad q = s*2+lh,
    // stored at (q ^ ((row>>1)&3))*8 (same swizzle as staging).
    v8s fah[2][2], fal[2][2], fbh[2][2], fbl[2][2];
#pragma unroll
    for (int i = 0; i < 2; ++i) {
      const int ma = wm * 64 + i * 32 + lr;
      const int swa = (ma >> 1) & 3;
#pragma unroll
      for (int s = 0; s < 2; ++s) {
        const int qa = (s * 2 + lh) ^ swa;
        fah[i][s] = *reinterpret_cast<const v8s*>(&As_h[ma * 32 + qa * 8]);
        fal[i][s] = *reinterpret_cast<const v8s*>(&As_l[ma * 32 + qa * 8]);
      }
      const int nb = wn * 64 + i * 32 + lr;
      const int swb = (nb >> 1) & 3;
#pragma unroll
      for (int s = 0; s < 2; ++s) {
        const int qb = (s * 2 + lh) ^ swb;
        fbh[i][s] = *reinterpret_cast<const v8s*>(&Bs_h[nb * 32 + qb * 8]);
        fbl[i][s] = *reinterpret_cast<const v8s*>(&Bs_l[nb * 32 + qb * 8]);
      }
    }
#pragma unroll
    for (int i = 0; i < 2; ++i)
#pragma unroll
      for (int j = 0; j < 2; ++j)
#pragma unroll
        for (int s = 0; s < 2; ++s) {
          acc[i][j] = __builtin_amdgcn_mfma_f32_32x32x16_bf16(fah[i][s], fbh[j][s], acc[i][j], 0, 0, 0);
          acc[i][j] = __builtin_amdgcn_mfma_f32_32x32x16_bf16(fah[i][s], fbl[j][s], acc[i][j], 0, 0, 0);
          acc[i][j] = __builtin_amdgcn_mfma_f32_32x32x16_bf16(fal[i][s], fbh[j][s], acc[i][j], 0, 0, 0);
        }
    __syncthreads();
  }

  // epilogue: C/D layout col = lane&31, row = (r&3) + 8*(r>>2) + 4*lh.
#pragma unroll
  for (int j = 0; j < 2; ++j) {
    const int nc = col0 + wn * 64 + j * 32 + lr;
    const float bz = bias[nc];
#pragma unroll
    for (int i = 0; i < 2; ++i) {
      const int mb0 = row0 + wm * 64 + i * 32 + lh * 4;
#pragma unroll
      for (int r = 0; r < 16; ++r) {
        const int row = mb0 + (r & 3) + 8 * (r >> 2);
        float v = acc[i][j][r] + bz;
        if (act) v = (v > 0.f) ? (v + 1.f) : __expf(v);
        Co[(size_t)row * 512 + nc] = __float2half(v);
      }
    }
  }
}

// ---------- final GEMM: out = attn @ Wo + bo (round-4 staging, 32x32x16) ----
__global__ __launch_bounds__(256) void gemm_split(
    const short* __restrict__ Ah, const short* __restrict__ Al,
    const short* __restrict__ Bh, const short* __restrict__ Bl,
    const float* __restrict__ bias, float* __restrict__ Cf)
{
  constexpr int K = 512;
  __shared__ short As_h[128 * 32], As_l[128 * 32], Bs_h[128 * 32], Bs_l[128 * 32];
  const int t = threadIdx.x;
  const int lane = t & 63;
  const int wv = t >> 6;
  const int wm = wv & 1, wn = wv >> 1;
  const int row0 = blockIdx.x * 128, col0 = blockIdx.y * 128;
  const int lr = lane & 31, lh = lane >> 5;

  v16f acc[2][2];
#pragma unroll
  for (int i = 0; i < 2; ++i)
#pragma unroll
    for (int j = 0; j < 2; ++j)
#pragma unroll
      for (int r = 0; r < 16; ++r) acc[i][j][r] = 0.f;

  const int srow = t >> 2;
  const int spq = t & 3;

  for (int k0 = 0; k0 < K; k0 += 32) {
#pragma unroll
    for (int c = 0; c < 2; ++c) {
      const int m = c * 64 + srow;
      const int q = spq ^ ((m >> 1) & 3);
      const size_t ga = (size_t)(row0 + m) * K + k0 + q * 8;
      const size_t gb = (size_t)(col0 + m) * K + k0 + q * 8;
      const int lo = c * 2048 + wv * 512;
      async_cp16(Ah + ga, As_h + lo);
      async_cp16(Al + ga, As_l + lo);
      async_cp16(Bh + gb, Bs_h + lo);
      async_cp16(Bl + gb, Bs_l + lo);
    }
    __syncthreads();

    v8s fah[2][2], fal[2][2], fbh[2][2], fbl[2][2];
#pragma unroll
    for (int i = 0; i < 2; ++i) {
      const int ma = wm * 64 + i * 32 + lr;
      const int swa = (ma >> 1) & 3;
#pragma unroll
      for (int s = 0; s < 2; ++s) {
        const int qa = (s * 2 + lh) ^ swa;
        fah[i][s] = *reinterpret_cast<const v8s*>(&As_h[ma * 32 + qa * 8]);
        fal[i][s] = *reinterpret_cast<const v8s*>(&As_l[ma * 32 + qa * 8]);
      }
      const int nb = wn * 64 + i * 32 + lr;
      const int swb = (nb >> 1) & 3;
#pragma unroll
      for (int s = 0; s < 2; ++s) {
        const int qb = (s * 2 + lh) ^ swb;
        fbh[i][s] = *reinterpret_cast<const v8s*>(&Bs_h[nb * 32 + qb * 8]);
        fbl[i][s] = *reinterpret_cast<const v8s*>(&Bs_l[nb * 32 + qb * 8]);
      }
    }
#pragma unroll
    for (int i = 0; i < 2; ++i)
#pragma unroll
      for (int j = 0; j < 2; ++j)
#pragma unroll
        for (int s = 0; s < 2; ++s) {
          acc[i][j] = __builtin_amdgcn_mfma_f32_32x32x16_bf16(fah[i][s], fbh[j][s], acc[i][j], 0, 0, 0);
          acc[i][j] = __builtin_amdgcn_mfma_f32_32x32x16_bf16(fah[i][s], fbl[j][s], acc[i][j], 0, 0, 0);
          acc[i][j] = __builtin_amdgcn_mfma_f32_32x32x16_bf16(fal[i][s], fbh[j][s], acc[i][j], 0, 0, 0);
        }
    __syncthreads();
  }

#pragma unroll
  for (int j = 0; j < 2; ++j) {
    const int nc = col0 + wn * 64 + j * 32 + lr;
    const float bz = bias[nc];
#pragma unroll
    for (int i = 0; i < 2; ++i) {
      const int mb0 = row0 + wm * 64 + i * 32 + lh * 4;
#pragma unroll
      for (int r = 0; r < 16; ++r) {
        const int row = mb0 + (r & 3) + 8 * (r >> 2);
        Cf[(size_t)row * 512 + nc] = acc[i][j][r] + bz;
      }
    }
  }
}

// ---------- KV stage 1 (round-4 verbatim): partial Kf^T@V and sum Kf ----------
__global__ __launch_bounds__(256) void kv_stage1(
    const __half* __restrict__ Kf, const __half* __restrict__ V,
    float* __restrict__ KVp, float* __restrict__ Ksp)
{
  const int sc = blockIdx.x, bh = blockIdx.y;
  const int b = bh >> 3, h = bh & 7;
  __shared__ float Ks[64][68];
  __shared__ float Vs[64][68];
  const int tid = threadIdx.x;
  const int dx = (tid >> 4) * 4;
  const int mx = (tid & 15) * 4;
  float acc[4][4];
#pragma unroll
  for (int i = 0; i < 4; ++i)
#pragma unroll
    for (int j = 0; j < 4; ++j) acc[i][j] = 0.f;
  float ksum_acc = 0.f;
  const size_t base = (size_t)b * Ss * Dd + (size_t)h * 64;

  for (int s0 = sc * 256; s0 < sc * 256 + 256; s0 += 64) {
#pragma unroll
    for (int l = 0; l < 2; ++l) {
      const int idx = tid + l * 256;
      const int rr = idx >> 3, cq = idx & 7;
      const size_t g = base + (size_t)(s0 + rr) * Dd + cq * 8;
      const __half2* k2 = reinterpret_cast<const __half2*>(Kf + g);
      const __half2* v2 = reinterpret_cast<const __half2*>(V + g);
#pragma unroll
      for (int u = 0; u < 4; ++u) {
        const float2 kf = __half22float2(k2[u]);
        const float2 vf = __half22float2(v2[u]);
        Ks[rr][cq * 8 + u * 2] = kf.x; Ks[rr][cq * 8 + u * 2 + 1] = kf.y;
        Vs[rr][cq * 8 + u * 2] = vf.x; Vs[rr][cq * 8 + u * 2 + 1] = vf.y;
      }
    }
    __syncthreads();
#pragma unroll 4
    for (int s = 0; s < 64; ++s) {
      const float4 kd = *reinterpret_cast<const float4*>(&Ks[s][dx]);
      const float4 vm = *reinterpret_cast<const float4*>(&Vs[s][mx]);
      const float ka[4] = {kd.x, kd.y, kd.z, kd.w};
      const float va[4] = {vm.x, vm.y, vm.z, vm.w};
#pragma unroll
      for (int i = 0; i < 4; ++i)
#pragma unroll
        for (int j = 0; j < 4; ++j) acc[i][j] = fmaf(ka[i], va[j], acc[i][j]);
    }
    if (tid < 64) {
#pragma unroll 8
      for (int s = 0; s < 64; ++s) ksum_acc += Ks[s][tid];
    }
    __syncthreads();
  }

  const size_t pb = (size_t)(sc * 64 + bh);
#pragma unroll
  for (int i = 0; i < 4; ++i) {
    const float4 ov = {acc[i][0], acc[i][1], acc[i][2], acc[i][3]};
    *reinterpret_cast<float4*>(&KVp[(pb * 64 + dx + i) * 64 + mx]) = ov;
  }
  if (tid < 64) Ksp[pb * 64 + tid] = ksum_acc;
}

// ---------- KV stage 2 (round-4 verbatim): sum 16 partials ----------
__global__ __launch_bounds__(256) void kv_stage2(
    const float* __restrict__ KVp, const float* __restrict__ Ksp,
    float* __restrict__ KV, float* __restrict__ Ksum)
{
  const int bh = blockIdx.x, t = threadIdx.x;
  for (int e = t; e < 4096; e += 256) {
    float s = 0.f;
#pragma unroll
    for (int sc = 0; sc < 16; ++sc) s += KVp[((size_t)(sc * 64 + bh) << 12) + e];
    KV[(size_t)bh * 4096 + e] = s;
  }
  if (t < 64) {
    float s = 0.f;
#pragma unroll
    for (int sc = 0; sc < 16; ++sc) s += Ksp[(size_t)(sc * 64 + bh) * 64 + t];
    Ksum[bh * 64 + t] = s;
  }
}

// ---------- attn (round-4 verbatim): Z * (Qf @ KV), bf16 hi/lo split out -----
__global__ __launch_bounds__(256) void attn_combine(
    const __half* __restrict__ Qf, const float* __restrict__ KV,
    const float* __restrict__ Ksum, short* __restrict__ Oh, short* __restrict__ Ol)
{
  const int h = blockIdx.y;
  const int r0 = blockIdx.x * 64;
  const int b = r0 >> 12;
  const int bh = b * Hh + h;
  __shared__ float Qs[64][68];
  __shared__ float KVs[64][68];
  __shared__ float Ksums[64];
  __shared__ float Zs[64];
  const int tid = threadIdx.x;

#pragma unroll
  for (int l = 0; l < 2; ++l) {
    const int idx = tid + l * 256;
    const int rr = idx >> 3, cq = idx & 7;
    const __half2* q2 = reinterpret_cast<const __half2*>(
        Qf + (size_t)(r0 + rr) * Dd + h * 64 + cq * 8);
#pragma unroll
    for (int u = 0; u < 4; ++u) {
      const float2 qf = __half22float2(q2[u]);
      Qs[rr][cq * 8 + u * 2] = qf.x; Qs[rr][cq * 8 + u * 2 + 1] = qf.y;
    }
  }
#pragma unroll
  for (int l = 0; l < 4; ++l) {
    const int idx = tid + l * 256;
    const int rr = idx >> 4, cq = idx & 15;
    *reinterpret_cast<float4*>(&KVs[rr][cq * 4]) = *reinterpret_cast<const float4*>(
        &KV[(size_t)bh * 4096 + rr * 64 + cq * 4]);
  }
  if (tid < 64) Ksums[tid] = Ksum[bh * 64 + tid];
  __syncthreads();

  if (tid < 64) {
    float z = 0.f;
#pragma unroll 8
    for (int d = 0; d < 64; ++d) z = fmaf(Qs[tid][d], Ksums[d], z);
    Zs[tid] = 1.f / (z + EPSF);
  }
  __syncthreads();

  const int rx = (tid >> 4) * 4, mx = (tid & 15) * 4;
  float acc[4][4];
#pragma unroll
  for (int i = 0; i < 4; ++i)
#pragma unroll
    for (int j = 0; j < 4; ++j) acc[i][j] = 0.f;

#pragma unroll 4
  for (int d = 0; d < 64; ++d) {
    const float4 vm = *reinterpret_cast<const float4*>(&KVs[d][mx]);
    const float va[4] = {vm.x, vm.y, vm.z, vm.w};
#pragma unroll
    for (int i = 0; i < 4; ++i) {
      const float q = Qs[rx + i][d];
#pragma unroll
      for (int j = 0; j < 4; ++j) acc[i][j] = fmaf(q, va[j], acc[i][j]);
    }
  }

#pragma unroll
  for (int i = 0; i < 4; ++i) {
    const float z = Zs[rx + i];
    short4 hv, lv;
    float o;
    o = acc[i][0] * z; hv.x = f2bf(o); lv.x = f2bf(o - bf2f(hv.x));
    o = acc[i][1] * z; hv.y = f2bf(o); lv.y = f2bf(o - bf2f(hv.y));
    o = acc[i][2] * z; hv.z = f2bf(o); lv.z = f2bf(o - bf2f(hv.z));
    o = acc[i][3] * z; hv.w = f2bf(o); lv.w = f2bf(o - bf2f(hv.w));
    const size_t off = (size_t)(r0 + rx + i) * Dd + h * 64 + mx;
    *reinterpret_cast<short4*>(&Oh[off]) = hv;
    *reinterpret_cast<short4*>(&Ol[off]) = lv;
  }
}

extern "C" void kernel_launch(void* const* d_in, const int* in_sizes, int n_in,
                              void* d_out, int out_size, void* d_ws, size_t ws_size,
                              hipStream_t stream) {
  const float* x  = (const float*)d_in[0];
  const float* Wq = (const float*)d_in[1];
  const float* bq = (const float*)d_in[2];
  const float* Wk = (const float*)d_in[3];
  const float* bk = (const float*)d_in[4];
  const float* Wv = (const float*)d_in[5];
  const float* bv = (const float*)d_in[6];
  const float* Wo = (const float*)d_in[7];
  const float* bo = (const float*)d_in[8];
  float* out = (float*)d_out;

  char* ws = (char*)d_ws;
  const size_t MB = (size_t)1 << 20;
  short*  x_hi  = (short*)(ws);              // 32 MB (later: attn_hi)
  short*  x_lo  = (short*)(ws + 32 * MB);    // 32 MB (later: attn_lo)
  short*  Wt_hi = (short*)(ws + 64 * MB);    // 2 MB (4 x 512x512)
  short*  Wt_lo = (short*)(ws + 66 * MB);    // 2 MB
  __half* Qf    = (__half*)(ws + 68 * MB);   // 32 MB
  __half* Kf    = (__half*)(ws + 100 * MB);  // 32 MB
  __half* Vv    = (__half*)(ws + 132 * MB);  // 32 MB
  float*  KVp   = (float*)(ws + 164 * MB);   // 17 MB
  float*  Ksp   = (float*)(ws + 181 * MB);   // 256 KB
  float*  KV    = (float*)(ws + 182 * MB);   // 1 MB
  float*  Ksum  = (float*)(ws + 183 * MB);   // 16 KB
  short*  attn_hi = x_hi;
  short*  attn_lo = x_lo;
  const size_t WSTEP = (size_t)512 * 512;

  prep_w<<<dim3(16, 16, 4), 256, 0, stream>>>(Wq, Wk, Wv, Wo, Wt_hi, Wt_lo);
  split_x<<<Mtot * Dd / 4 / 256, 256, 0, stream>>>(x, x_hi, x_lo, Mtot * Dd / 4);

  gemm_qkv<<<dim3(Mtot / 128, 12), 256, 0, stream>>>(
      x_hi, x_lo, Wt_hi, Wt_lo, bq, bk, bv, Qf, Kf, Vv);

  kv_stage1<<<dim3(16, 64), 256, 0, stream>>>(Kf, Vv, KVp, Ksp);
  kv_stage2<<<64, 256, 0, stream>>>(KVp, Ksp, KV, Ksum);
  attn_combine<<<dim3(Mtot / 64, Hh), 256, 0, stream>>>(Qf, KV, Ksum, attn_hi, attn_lo);

  gemm_split<<<dim3(Mtot / 128, 4), 256, 0, stream>>>(
      attn_hi, attn_lo, Wt_hi + 3 * WSTEP, Wt_lo + 3 * WSTEP, bo, out);
}

// Round 5
// 427.568 us; speedup vs baseline: 1.1513x; 1.0184x over previous
//
#include <hip/hip_runtime.h>
#include <hip/hip_fp16.h>

// LinearAttention (phi = elu+1). B=8 S=4096 D=512 H=8 DH=64.
// Round 9: LDS-read-bandwidth fix. Diagnosis: per wave per K-step the
// round-4/8 structure reads 16 KB from LDS for 24 MFMA; LDS BW is per-CU
// while MFMA is per-SIMD, giving a hard MfmaUtil ceiling ~40% (measured
// 38.7/41.5). Fix: block tile 256x128 with per-wave output 128x64 ->
// 12 KB LDS reads per 48 MFMA per K-step (2x FLOP per LDS byte), which
// moves the balance point to ~100%. 32x32x16 MFMA core and all operand /
// C-D layouts are round-8 verbatim (hardware-verified). Staging keeps the
// verified wave-uniform-dest + q-XOR pre-swizzled global source pattern,
// re-derived for 256 rows (chunk ci = c*256 + t -> dest c*2048 + wv*512).
// LDS 48 KB/block, acc = 4x2 f32x16 = 128 VGPR, launch_bounds(256,2).
// Non-GEMM kernels verbatim.
// ws: [x_hi 32|x_lo 32|Wt_hi 2|Wt_lo 2|Qf 32|Kf 32|V 32|KVp 17|Ksp|KV|Ksum]

constexpr int Ss = 4096;
constexpr int Dd = 512;
constexpr int Hh = 8;
constexpr int Mtot = 8 * 4096;  // 32768
constexpr float EPSF = 1e-6f;

typedef short v8s __attribute__((ext_vector_type(8)));
typedef float v16f __attribute__((ext_vector_type(16)));

__device__ __forceinline__ short f2bf(float f) {  // RNE fp32 -> bf16
  unsigned u = __float_as_uint(f);
  u += 0x7fff + ((u >> 16) & 1);
  return (short)(u >> 16);
}
__device__ __forceinline__ float bf2f(short s) {
  return __uint_as_float(((unsigned)(unsigned short)s) << 16);
}
__device__ __forceinline__ void async_cp16(const void* g, void* l) {
  __builtin_amdgcn_global_load_lds((__attribute__((address_space(1))) void*)g,
                                   (__attribute__((address_space(3))) void*)l, 16, 0, 0);
}

// ---------- weight prep: W[512][512] -> Wt[n][k] bf16 hi/lo (4 matrices) ----------
__global__ __launch_bounds__(256) void prep_w(
    const float* __restrict__ W0, const float* __restrict__ W1,
    const float* __restrict__ W2, const float* __restrict__ W3,
    short* __restrict__ Th, short* __restrict__ Tl)
{
  const float* W = (blockIdx.z == 0) ? W0 : (blockIdx.z == 1) ? W1
                  : (blockIdx.z == 2) ? W2 : W3;
  short* th = Th + (size_t)blockIdx.z * 512 * 512;
  short* tl = Tl + (size_t)blockIdx.z * 512 * 512;
  __shared__ float tile[32][33];
  const int t = threadIdx.x;
  const int tx = t & 31, ty = t >> 5;  // 32 x 8
  const int k0 = blockIdx.x * 32, n0 = blockIdx.y * 32;
#pragma unroll
  for (int r = 0; r < 32; r += 8)
    tile[ty + r][tx] = W[(size_t)(k0 + ty + r) * 512 + n0 + tx];
  __syncthreads();
#pragma unroll
  for (int r = 0; r < 32; r += 8) {
    const float v = tile[tx][ty + r];  // = W[k0+tx][n0+ty+r]
    const short h = f2bf(v);
    const short l = f2bf(v - bf2f(h));
    th[(size_t)(n0 + ty + r) * 512 + k0 + tx] = h;
    tl[(size_t)(n0 + ty + r) * 512 + k0 + tx] = l;
  }
}

// ---------- x split: fp32 -> bf16 hi/lo ----------
__global__ __launch_bounds__(256) void split_x(
    const float* __restrict__ X, short* __restrict__ H, short* __restrict__ L, int n4)
{
  const int i = blockIdx.x * 256 + threadIdx.x;
  if (i >= n4) return;
  const float4 x = reinterpret_cast<const float4*>(X)[i];
  short4 h, l;
  h.x = f2bf(x.x); l.x = f2bf(x.x - bf2f(h.x));
  h.y = f2bf(x.y); l.y = f2bf(x.y - bf2f(h.y));
  h.z = f2bf(x.z); l.z = f2bf(x.z - bf2f(h.z));
  h.w = f2bf(x.w); l.w = f2bf(x.w - bf2f(h.w));
  reinterpret_cast<short4*>(H)[i] = h;
  reinterpret_cast<short4*>(L)[i] = l;
}

// ---------- shared GEMM core: 256x128 block, 4 waves of 128x64, 32x32x16 ----
// As: 256x32 shorts (hi,lo), Bs: 128x32 (hi,lo). Staging: chunk ci=c*256+t,
// row=ci>>2, q=ci&3, global quad qs=q^((row>>1)&3), dest=c*2048+wv*512
// (wave-uniform; HW adds lane*16B). Fragments: row=lane&31, k-half=lane>>5,
// slot qa=(s*2+lh)^((row>>1)&3). C/D: col=lane&31, row=(r&3)+8*(r>>2)+4*lh.
__device__ __forceinline__ void gemm_core(
    const short* __restrict__ Ah, const short* __restrict__ Al,
    const short* __restrict__ Bh, const short* __restrict__ Bl,
    short* As_h, short* As_l, short* Bs_h, short* Bs_l,
    int row0, int col0, int wv, int wm, int wn, int lr, int lh,
    int srow, int spq, v16f (&acc)[4][2])
{
  constexpr int K = 512;
#pragma unroll
  for (int i = 0; i < 4; ++i)
#pragma unroll
    for (int j = 0; j < 2; ++j)
#pragma unroll
      for (int r = 0; r < 16; ++r) acc[i][j][r] = 0.f;

  for (int k0 = 0; k0 < K; k0 += 32) {
#pragma unroll
    for (int c = 0; c < 4; ++c) {
      const int m = c * 64 + srow;                  // 0..255
      const int q = spq ^ ((m >> 1) & 3);
      const size_t ga = (size_t)(row0 + m) * K + k0 + q * 8;
      const int lo = c * 2048 + wv * 512;
      async_cp16(Ah + ga, As_h + lo);
      async_cp16(Al + ga, As_l + lo);
      if (c < 2) {                                  // m < 128 here
        const size_t gb = (size_t)(col0 + m) * K + k0 + q * 8;
        async_cp16(Bh + gb, Bs_h + lo);
        async_cp16(Bl + gb, Bs_l + lo);
      }
    }
    __syncthreads();

    v8s fbh[2][2], fbl[2][2];
#pragma unroll
    for (int j = 0; j < 2; ++j) {
      const int nb = wn * 64 + j * 32 + lr;
      const int swb = (nb >> 1) & 3;
#pragma unroll
      for (int s = 0; s < 2; ++s) {
        const int qb = (s * 2 + lh) ^ swb;
        fbh[j][s] = *reinterpret_cast<const v8s*>(&Bs_h[nb * 32 + qb * 8]);
        fbl[j][s] = *reinterpret_cast<const v8s*>(&Bs_l[nb * 32 + qb * 8]);
      }
    }
#pragma unroll
    for (int i = 0; i < 4; ++i) {
      const int ma = wm * 128 + i * 32 + lr;
      const int swa = (ma >> 1) & 3;
      v8s fah[2], fal[2];
#pragma unroll
      for (int s = 0; s < 2; ++s) {
        const int qa = (s * 2 + lh) ^ swa;
        fah[s] = *reinterpret_cast<const v8s*>(&As_h[ma * 32 + qa * 8]);
        fal[s] = *reinterpret_cast<const v8s*>(&As_l[ma * 32 + qa * 8]);
      }
#pragma unroll
      for (int j = 0; j < 2; ++j)
#pragma unroll
        for (int s = 0; s < 2; ++s) {
          acc[i][j] = __builtin_amdgcn_mfma_f32_32x32x16_bf16(fah[s], fbh[j][s], acc[i][j], 0, 0, 0);
          acc[i][j] = __builtin_amdgcn_mfma_f32_32x32x16_bf16(fah[s], fbl[j][s], acc[i][j], 0, 0, 0);
          acc[i][j] = __builtin_amdgcn_mfma_f32_32x32x16_bf16(fal[s], fbh[j][s], acc[i][j], 0, 0, 0);
        }
    }
    __syncthreads();
  }
}

// ---------- fused QKV GEMM: grid (Mtot/256, 12), y = mat*4 + colblock ----
__global__ __launch_bounds__(256, 2) void gemm_qkv(
    const short* __restrict__ Ah, const short* __restrict__ Al,
    const short* __restrict__ Wth, const short* __restrict__ Wtl,
    const float* __restrict__ bq, const float* __restrict__ bk,
    const float* __restrict__ bv,
    __half* __restrict__ Qf, __half* __restrict__ Kf, __half* __restrict__ Vv)
{
  __shared__ short As_h[256 * 32], As_l[256 * 32];  // 16 KB each
  __shared__ short Bs_h[128 * 32], Bs_l[128 * 32];  // 8 KB each

  const int mat = blockIdx.y >> 2;
  const int col0 = (blockIdx.y & 3) * 128;
  const int row0 = blockIdx.x * 256;
  const short* Bh = Wth + (size_t)mat * 512 * 512;
  const short* Bl = Wtl + (size_t)mat * 512 * 512;
  const float* bias = (mat == 0) ? bq : (mat == 1) ? bk : bv;
  __half* Co = (mat == 0) ? Qf : (mat == 1) ? Kf : Vv;
  const int act = (mat < 2);

  const int t = threadIdx.x;
  const int lane = t & 63;
  const int wv = t >> 6;
  const int wm = wv & 1, wn = wv >> 1;
  const int lr = lane & 31, lh = lane >> 5;
  const int srow = t >> 2, spq = t & 3;

  v16f acc[4][2];
  gemm_core(Ah, Al, Bh, Bl, As_h, As_l, Bs_h, Bs_l,
            row0, col0, wv, wm, wn, lr, lh, srow, spq, acc);

#pragma unroll
  for (int j = 0; j < 2; ++j) {
    const int nc = col0 + wn * 64 + j * 32 + lr;
    const float bz = bias[nc];
#pragma unroll
    for (int i = 0; i < 4; ++i) {
      const int mb0 = row0 + wm * 128 + i * 32 + lh * 4;
#pragma unroll
      for (int r = 0; r < 16; ++r) {
        const int row = mb0 + (r & 3) + 8 * (r >> 2);
        float v = acc[i][j][r] + bz;
        if (act) v = (v > 0.f) ? (v + 1.f) : __expf(v);
        Co[(size_t)row * 512 + nc] = __float2half(v);
      }
    }
  }
}

// ---------- final GEMM: out = attn @ Wo + bo, grid (Mtot/256, 4) ----
__global__ __launch_bounds__(256, 2) void gemm_split(
    const short* __restrict__ Ah, const short* __restrict__ Al,
    const short* __restrict__ Bh, const short* __restrict__ Bl,
    const float* __restrict__ bias, float* __restrict__ Cf)
{
  __shared__ short As_h[256 * 32], As_l[256 * 32];
  __shared__ short Bs_h[128 * 32], Bs_l[128 * 32];

  const int row0 = blockIdx.x * 256, col0 = blockIdx.y * 128;
  const int t = threadIdx.x;
  const int lane = t & 63;
  const int wv = t >> 6;
  const int wm = wv & 1, wn = wv >> 1;
  const int lr = lane & 31, lh = lane >> 5;
  const int srow = t >> 2, spq = t & 3;

  v16f acc[4][2];
  gemm_core(Ah, Al, Bh, Bl, As_h, As_l, Bs_h, Bs_l,
            row0, col0, wv, wm, wn, lr, lh, srow, spq, acc);

#pragma unroll
  for (int j = 0; j < 2; ++j) {
    const int nc = col0 + wn * 64 + j * 32 + lr;
    const float bz = bias[nc];
#pragma unroll
    for (int i = 0; i < 4; ++i) {
      const int mb0 = row0 + wm * 128 + i * 32 + lh * 4;
#pragma unroll
      for (int r = 0; r < 16; ++r) {
        const int row = mb0 + (r & 3) + 8 * (r >> 2);
        Cf[(size_t)row * 512 + nc] = acc[i][j][r] + bz;
      }
    }
  }
}

// ---------- KV stage 1 (verbatim): partial Kf^T@V and sum Kf ----------
__global__ __launch_bounds__(256) void kv_stage1(
    const __half* __restrict__ Kf, const __half* __restrict__ V,
    float* __restrict__ KVp, float* __restrict__ Ksp)
{
  const int sc = blockIdx.x, bh = blockIdx.y;
  const int b = bh >> 3, h = bh & 7;
  __shared__ float Ks[64][68];
  __shared__ float Vs[64][68];
  const int tid = threadIdx.x;
  const int dx = (tid >> 4) * 4;
  const int mx = (tid & 15) * 4;
  float acc[4][4];
#pragma unroll
  for (int i = 0; i < 4; ++i)
#pragma unroll
    for (int j = 0; j < 4; ++j) acc[i][j] = 0.f;
  float ksum_acc = 0.f;
  const size_t base = (size_t)b * Ss * Dd + (size_t)h * 64;

  for (int s0 = sc * 256; s0 < sc * 256 + 256; s0 += 64) {
#pragma unroll
    for (int l = 0; l < 2; ++l) {
      const int idx = tid + l * 256;
      const int rr = idx >> 3, cq = idx & 7;
      const size_t g = base + (size_t)(s0 + rr) * Dd + cq * 8;
      const __half2* k2 = reinterpret_cast<const __half2*>(Kf + g);
      const __half2* v2 = reinterpret_cast<const __half2*>(V + g);
#pragma unroll
      for (int u = 0; u < 4; ++u) {
        const float2 kf = __half22float2(k2[u]);
        const float2 vf = __half22float2(v2[u]);
        Ks[rr][cq * 8 + u * 2] = kf.x; Ks[rr][cq * 8 + u * 2 + 1] = kf.y;
        Vs[rr][cq * 8 + u * 2] = vf.x; Vs[rr][cq * 8 + u * 2 + 1] = vf.y;
      }
    }
    __syncthreads();
#pragma unroll 4
    for (int s = 0; s < 64; ++s) {
      const float4 kd = *reinterpret_cast<const float4*>(&Ks[s][dx]);
      const float4 vm = *reinterpret_cast<const float4*>(&Vs[s][mx]);
      const float ka[4] = {kd.x, kd.y, kd.z, kd.w};
      const float va[4] = {vm.x, vm.y, vm.z, vm.w};
#pragma unroll
      for (int i = 0; i < 4; ++i)
#pragma unroll
        for (int j = 0; j < 4; ++j) acc[i][j] = fmaf(ka[i], va[j], acc[i][j]);
    }
    if (tid < 64) {
#pragma unroll 8
      for (int s = 0; s < 64; ++s) ksum_acc += Ks[s][tid];
    }
    __syncthreads();
  }

  const size_t pb = (size_t)(sc * 64 + bh);
#pragma unroll
  for (int i = 0; i < 4; ++i) {
    const float4 ov = {acc[i][0], acc[i][1], acc[i][2], acc[i][3]};
    *reinterpret_cast<float4*>(&KVp[(pb * 64 + dx + i) * 64 + mx]) = ov;
  }
  if (tid < 64) Ksp[pb * 64 + tid] = ksum_acc;
}

// ---------- KV stage 2 (verbatim): sum 16 partials ----------
__global__ __launch_bounds__(256) void kv_stage2(
    const float* __restrict__ KVp, const float* __restrict__ Ksp,
    float* __restrict__ KV, float* __restrict__ Ksum)
{
  const int bh = blockIdx.x, t = threadIdx.x;
  for (int e = t; e < 4096; e += 256) {
    float s = 0.f;
#pragma unroll
    for (int sc = 0; sc < 16; ++sc) s += KVp[((size_t)(sc * 64 + bh) << 12) + e];
    KV[(size_t)bh * 4096 + e] = s;
  }
  if (t < 64) {
    float s = 0.f;
#pragma unroll
    for (int sc = 0; sc < 16; ++sc) s += Ksp[(size_t)(sc * 64 + bh) * 64 + t];
    Ksum[bh * 64 + t] = s;
  }
}

// ---------- attn (verbatim): Z * (Qf @ KV), bf16 hi/lo split out -----
__global__ __launch_bounds__(256) void attn_combine(
    const __half* __restrict__ Qf, const float* __restrict__ KV,
    const float* __restrict__ Ksum, short* __restrict__ Oh, short* __restrict__ Ol)
{
  const int h = blockIdx.y;
  const int r0 = blockIdx.x * 64;
  const int b = r0 >> 12;
  const int bh = b * Hh + h;
  __shared__ float Qs[64][68];
  __shared__ float KVs[64][68];
  __shared__ float Ksums[64];
  __shared__ float Zs[64];
  const int tid = threadIdx.x;

#pragma unroll
  for (int l = 0; l < 2; ++l) {
    const int idx = tid + l * 256;
    const int rr = idx >> 3, cq = idx & 7;
    const __half2* q2 = reinterpret_cast<const __half2*>(
        Qf + (size_t)(r0 + rr) * Dd + h * 64 + cq * 8);
#pragma unroll
    for (int u = 0; u < 4; ++u) {
      const float2 qf = __half22float2(q2[u]);
      Qs[rr][cq * 8 + u * 2] = qf.x; Qs[rr][cq * 8 + u * 2 + 1] = qf.y;
    }
  }
#pragma unroll
  for (int l = 0; l < 4; ++l) {
    const int idx = tid + l * 256;
    const int rr = idx >> 4, cq = idx & 15;
    *reinterpret_cast<float4*>(&KVs[rr][cq * 4]) = *reinterpret_cast<const float4*>(
        &KV[(size_t)bh * 4096 + rr * 64 + cq * 4]);
  }
  if (tid < 64) Ksums[tid] = Ksum[bh * 64 + tid];
  __syncthreads();

  if (tid < 64) {
    float z = 0.f;
#pragma unroll 8
    for (int d = 0; d < 64; ++d) z = fmaf(Qs[tid][d], Ksums[d], z);
    Zs[tid] = 1.f / (z + EPSF);
  }
  __syncthreads();

  const int rx = (tid >> 4) * 4, mx = (tid & 15) * 4;
  float acc[4][4];
#pragma unroll
  for (int i = 0; i < 4; ++i)
#pragma unroll
    for (int j = 0; j < 4; ++j) acc[i][j] = 0.f;

#pragma unroll 4
  for (int d = 0; d < 64; ++d) {
    const float4 vm = *reinterpret_cast<const float4*>(&KVs[d][mx]);
    const float va[4] = {vm.x, vm.y, vm.z, vm.w};
#pragma unroll
    for (int i = 0; i < 4; ++i) {
      const float q = Qs[rx + i][d];
#pragma unroll
      for (int j = 0; j < 4; ++j) acc[i][j] = fmaf(q, va[j], acc[i][j]);
    }
  }

#pragma unroll
  for (int i = 0; i < 4; ++i) {
    const float z = Zs[rx + i];
    short4 hv, lv;
    float o;
    o = acc[i][0] * z; hv.x = f2bf(o); lv.x = f2bf(o - bf2f(hv.x));
    o = acc[i][1] * z; hv.y = f2bf(o); lv.y = f2bf(o - bf2f(hv.y));
    o = acc[i][2] * z; hv.z = f2bf(o); lv.z = f2bf(o - bf2f(hv.z));
    o = acc[i][3] * z; hv.w = f2bf(o); lv.w = f2bf(o - bf2f(hv.w));
    const size_t off = (size_t)(r0 + rx + i) * Dd + h * 64 + mx;
    *reinterpret_cast<short4*>(&Oh[off]) = hv;
    *reinterpret_cast<short4*>(&Ol[off]) = lv;
  }
}

extern "C" void kernel_launch(void* const* d_in, const int* in_sizes, int n_in,
                              void* d_out, int out_size, void* d_ws, size_t ws_size,
                              hipStream_t stream) {
  const float* x  = (const float*)d_in[0];
  const float* Wq = (const float*)d_in[1];
  const float* bq = (const float*)d_in[2];
  const float* Wk = (const float*)d_in[3];
  const float* bk = (const float*)d_in[4];
  const float* Wv = (const float*)d_in[5];
  const float* bv = (const float*)d_in[6];
  const float* Wo = (const float*)d_in[7];
  const float* bo = (const float*)d_in[8];
  float* out = (float*)d_out;

  char* ws = (char*)d_ws;
  const size_t MB = (size_t)1 << 20;
  short*  x_hi  = (short*)(ws);              // 32 MB (later: attn_hi)
  short*  x_lo  = (short*)(ws + 32 * MB);    // 32 MB (later: attn_lo)
  short*  Wt_hi = (short*)(ws + 64 * MB);    // 2 MB (4 x 512x512)
  short*  Wt_lo = (short*)(ws + 66 * MB);    // 2 MB
  __half* Qf    = (__half*)(ws + 68 * MB);   // 32 MB
  __half* Kf    = (__half*)(ws + 100 * MB);  // 32 MB
  __half* Vv    = (__half*)(ws + 132 * MB);  // 32 MB
  float*  KVp   = (float*)(ws + 164 * MB);   // 17 MB
  float*  Ksp   = (float*)(ws + 181 * MB);   // 256 KB
  float*  KV    = (float*)(ws + 182 * MB);   // 1 MB
  float*  Ksum  = (float*)(ws + 183 * MB);   // 16 KB
  short*  attn_hi = x_hi;
  short*  attn_lo = x_lo;
  const size_t WSTEP = (size_t)512 * 512;

  prep_w<<<dim3(16, 16, 4), 256, 0, stream>>>(Wq, Wk, Wv, Wo, Wt_hi, Wt_lo);
  split_x<<<Mtot * Dd / 4 / 256, 256, 0, stream>>>(x, x_hi, x_lo, Mtot * Dd / 4);

  gemm_qkv<<<dim3(Mtot / 256, 12), 256, 0, stream>>>(
      x_hi, x_lo, Wt_hi, Wt_lo, bq, bk, bv, Qf, Kf, Vv);

  kv_stage1<<<dim3(16, 64), 256, 0, stream>>>(Kf, Vv, KVp, Ksp);
  kv_stage2<<<64, 256, 0, stream>>>(KVp, Ksp, KV, Ksum);
  attn_combine<<<dim3(Mtot / 64, Hh), 256, 0, stream>>>(Qf, KV, Ksum, attn_hi, attn_lo);

  gemm_split<<<dim3(Mtot / 256, 4), 256, 0, stream>>>(
      attn_hi, attn_lo, Wt_hi + 3 * WSTEP, Wt_lo + 3 * WSTEP, bo, out);
}